// Round 6
// baseline (427.381 us; speedup 1.0000x reference)
//
#include <hip/hip_runtime.h>
#include <hip/hip_bf16.h>

#define NN 100000
#define EE 1600000
#define BSZ 512    // dst-nodes per coarse bucket
#define NBKT 196   // ceil(NN/BSZ)
#define CHUNK 8192 // edges per coarse chunk
#define NCH 196    // ceil(EE/CHUNK)

// ---------------- bf16 helpers ----------------
__device__ inline unsigned short bf16_of(float f) {
    __hip_bfloat16 h = __float2bfloat16(f);   // RNE
    return *reinterpret_cast<unsigned short*>(&h);
}
__device__ inline float bflo(unsigned u) { return __uint_as_float(u << 16); }
__device__ inline float bfhi(unsigned u) { return __uint_as_float(u & 0xffff0000u); }

// ---------------- CSR build ----------------

__global__ __launch_bounds__(256)
void k_ccount(const int* __restrict__ ei, int* __restrict__ ccount) {
    __shared__ int hist[NBKT];
    int tid = threadIdx.x;
    int e0 = blockIdx.x * CHUNK;
    int e1 = e0 + CHUNK; if (e1 > EE) e1 = EE;
    for (int i = tid; i < NBKT; i += 256) hist[i] = 0;
    __syncthreads();
    for (int e = e0 + tid; e < e1; e += 256)
        atomicAdd(&hist[ei[EE + e] >> 9], 1);
    __syncthreads();
    for (int i = tid; i < NBKT; i += 256)
        if (hist[i]) atomicAdd(&ccount[i], hist[i]);
}

__global__ void k_cscan(const int* __restrict__ ccount, int* __restrict__ cbase,
                        int* __restrict__ gcur) {
    __shared__ int s[256];
    int tid = threadIdx.x;
    int v = (tid < NBKT) ? ccount[tid] : 0;
    s[tid] = v;
    __syncthreads();
    for (int off = 1; off < 256; off <<= 1) {
        int t = (tid >= off) ? s[tid - off] : 0;
        __syncthreads();
        if (tid >= off) s[tid] += t;
        __syncthreads();
    }
    if (tid < NBKT) {
        int excl = s[tid] - v;
        cbase[tid] = excl;
        gcur[tid] = excl;
    }
    if (tid == NBKT - 1) cbase[NBKT] = s[tid];
}

__global__ __launch_bounds__(256)
void k_coarse(const int* __restrict__ ei, int* __restrict__ gcur, int2* __restrict__ pairs) {
    __shared__ int hist[NBKT];
    __shared__ int base[NBKT];
    __shared__ int curs[NBKT];
    int tid = threadIdx.x;
    int e0 = blockIdx.x * CHUNK;
    int e1 = e0 + CHUNK; if (e1 > EE) e1 = EE;
    for (int i = tid; i < NBKT; i += 256) hist[i] = 0;
    __syncthreads();
    for (int e = e0 + tid; e < e1; e += 256)
        atomicAdd(&hist[ei[EE + e] >> 9], 1);
    __syncthreads();
    for (int i = tid; i < NBKT; i += 256) {
        base[i] = atomicAdd(&gcur[i], hist[i]);
        curs[i] = 0;
    }
    __syncthreads();
    for (int e = e0 + tid; e < e1; e += 256) {
        int src = ei[e];
        int dst = ei[EE + e];
        int b = dst >> 9;
        int off = atomicAdd(&curs[b], 1);
        pairs[base[b] + off] = make_int2(src, dst);
    }
}

__global__ __launch_bounds__(512)
void k_fine(const int* __restrict__ cbase, const int2* __restrict__ pairs,
            int* __restrict__ rs, int* __restrict__ esrc) {
    __shared__ int deg[BSZ];
    __shared__ int s[BSZ];
    int b = blockIdx.x;
    int n0 = b * BSZ;
    int nlocal = NN - n0; if (nlocal > BSZ) nlocal = BSZ;
    int tid = threadIdx.x;
    deg[tid] = 0;
    __syncthreads();
    int e0 = cbase[b], e1 = cbase[b + 1];
    for (int e = e0 + tid; e < e1; e += 512)
        atomicAdd(&deg[pairs[e].y - n0], 1);
    __syncthreads();
    int v = deg[tid];
    s[tid] = v;
    __syncthreads();
    for (int off = 1; off < 512; off <<= 1) {
        int t = (tid >= off) ? s[tid - off] : 0;
        __syncthreads();
        if (tid >= off) s[tid] += t;
        __syncthreads();
    }
    int excl = s[tid] - v;
    if (tid < nlocal) rs[n0 + tid] = e0 + excl;
    if (b == NBKT - 1 && tid == 0) rs[NN] = EE;
    deg[tid] = e0 + excl;
    __syncthreads();
    for (int e = e0 + tid; e < e1; e += 512) {
        int2 p = pairs[e];
        int pos = atomicAdd(&deg[p.y - n0], 1);
        esrc[pos] = p.x;
    }
}

// ---------------- fp32 -> bf16 table conversion ----------------
__global__ void k_tobf(const float4* __restrict__ src, ushort4* __restrict__ dst) {
    int i = blockIdx.x * 256 + threadIdx.x;
    if (i >= NN * 16) return;
    float4 v = src[i];
    dst[i] = make_ushort4(bf16_of(v.x), bf16_of(v.y), bf16_of(v.z), bf16_of(v.w));
}

// ---------------- fused SAGE layer: gather-mean -> split-K GEMM -> epilogue ----------------
// tile = 64 nodes, 256 threads. Phase 1: wave-per-node bf16 gather (8 feat-lanes
// x 8 slots, unroll-2) of mean directly into transposed LDS A-tile. Phase 2/3:
// split-K GEMM (mean/Wl then A2/Wr) + bias + L2-norm + BN-stat epilogue.
__global__ __launch_bounds__(256, 4)
void k_sagefused(const unsigned short* __restrict__ gtab,  // bf16 gather table (N,64)
                 const float* A2,                          // x / h1raw (N,64) -- may alias out
                 const float* __restrict__ Wl, const float* __restrict__ Wr,
                 const float* __restrict__ bias,
                 float* out, ushort4* __restrict__ outbf,  // optional bf16 copy
                 float* __restrict__ sumf, float* __restrict__ ssqf,
                 const float* __restrict__ sc, const float* __restrict__ sh,
                 const int* __restrict__ rs, const int* __restrict__ esrc) {
    __shared__ float Alds[64 * 64];
    __shared__ float Wlds[64 * 64];
    const int tid = threadIdx.x;
    const int base = blockIdx.x * 64;
    const int lane = tid & 63;
    const int wv = tid >> 6;
    const int c8 = lane & 7;      // feature octet (8 feats = 1 uint4)
    const int slot = lane >> 3;   // neighbor slot 0..7
    const uint4* xb = (const uint4*)gtab;

    // ---- phase 1: gather means for 16 nodes per wave into Alds[k][node]
    float4 scl, sch, shl, shh;
    if (sc) {
        scl = ((const float4*)sc)[2 * c8]; sch = ((const float4*)sc)[2 * c8 + 1];
        shl = ((const float4*)sh)[2 * c8]; shh = ((const float4*)sh)[2 * c8 + 1];
    }
    for (int t = 0; t < 16; ++t) {
        int nl = wv * 16 + t;
        int gn = base + nl;
        float a[8] = {0.f, 0.f, 0.f, 0.f, 0.f, 0.f, 0.f, 0.f};
        int cnt = 1;
        if (gn < NN) {
            int s0 = rs[gn], s1 = rs[gn + 1];
            int d = s1 - s0; if (d > 1) cnt = d;
            if (sc) {
                int p = s0 + slot;
                for (; p + 8 < s1; p += 16) {
                    uint4 va = xb[esrc[p] * 8 + c8];
                    uint4 vb = xb[esrc[p + 8] * 8 + c8];
                    a[0] += fmaxf(fmaf(bflo(va.x), scl.x, shl.x), 0.f);
                    a[1] += fmaxf(fmaf(bfhi(va.x), scl.y, shl.y), 0.f);
                    a[2] += fmaxf(fmaf(bflo(va.y), scl.z, shl.z), 0.f);
                    a[3] += fmaxf(fmaf(bfhi(va.y), scl.w, shl.w), 0.f);
                    a[4] += fmaxf(fmaf(bflo(va.z), sch.x, shh.x), 0.f);
                    a[5] += fmaxf(fmaf(bfhi(va.z), sch.y, shh.y), 0.f);
                    a[6] += fmaxf(fmaf(bflo(va.w), sch.z, shh.z), 0.f);
                    a[7] += fmaxf(fmaf(bfhi(va.w), sch.w, shh.w), 0.f);
                    a[0] += fmaxf(fmaf(bflo(vb.x), scl.x, shl.x), 0.f);
                    a[1] += fmaxf(fmaf(bfhi(vb.x), scl.y, shl.y), 0.f);
                    a[2] += fmaxf(fmaf(bflo(vb.y), scl.z, shl.z), 0.f);
                    a[3] += fmaxf(fmaf(bfhi(vb.y), scl.w, shl.w), 0.f);
                    a[4] += fmaxf(fmaf(bflo(vb.z), sch.x, shh.x), 0.f);
                    a[5] += fmaxf(fmaf(bfhi(vb.z), sch.y, shh.y), 0.f);
                    a[6] += fmaxf(fmaf(bflo(vb.w), sch.z, shh.z), 0.f);
                    a[7] += fmaxf(fmaf(bfhi(vb.w), sch.w, shh.w), 0.f);
                }
                if (p < s1) {
                    uint4 va = xb[esrc[p] * 8 + c8];
                    a[0] += fmaxf(fmaf(bflo(va.x), scl.x, shl.x), 0.f);
                    a[1] += fmaxf(fmaf(bfhi(va.x), scl.y, shl.y), 0.f);
                    a[2] += fmaxf(fmaf(bflo(va.y), scl.z, shl.z), 0.f);
                    a[3] += fmaxf(fmaf(bfhi(va.y), scl.w, shl.w), 0.f);
                    a[4] += fmaxf(fmaf(bflo(va.z), sch.x, shh.x), 0.f);
                    a[5] += fmaxf(fmaf(bfhi(va.z), sch.y, shh.y), 0.f);
                    a[6] += fmaxf(fmaf(bflo(va.w), sch.z, shh.z), 0.f);
                    a[7] += fmaxf(fmaf(bfhi(va.w), sch.w, shh.w), 0.f);
                }
            } else {
                int p = s0 + slot;
                for (; p + 8 < s1; p += 16) {
                    uint4 va = xb[esrc[p] * 8 + c8];
                    uint4 vb = xb[esrc[p + 8] * 8 + c8];
                    a[0] += bflo(va.x) + bflo(vb.x); a[1] += bfhi(va.x) + bfhi(vb.x);
                    a[2] += bflo(va.y) + bflo(vb.y); a[3] += bfhi(va.y) + bfhi(vb.y);
                    a[4] += bflo(va.z) + bflo(vb.z); a[5] += bfhi(va.z) + bfhi(vb.z);
                    a[6] += bflo(va.w) + bflo(vb.w); a[7] += bfhi(va.w) + bfhi(vb.w);
                }
                if (p < s1) {
                    uint4 va = xb[esrc[p] * 8 + c8];
                    a[0] += bflo(va.x); a[1] += bfhi(va.x);
                    a[2] += bflo(va.y); a[3] += bfhi(va.y);
                    a[4] += bflo(va.z); a[5] += bfhi(va.z);
                    a[6] += bflo(va.w); a[7] += bfhi(va.w);
                }
            }
        }
#pragma unroll
        for (int j = 0; j < 8; ++j) {
            a[j] += __shfl_xor(a[j], 8, 64);
            a[j] += __shfl_xor(a[j], 16, 64);
            a[j] += __shfl_xor(a[j], 32, 64);
        }
        if (slot == 0) {
            float inv = 1.0f / (float)cnt;
#pragma unroll
            for (int j = 0; j < 8; ++j)
                Alds[(c8 * 8 + j) * 64 + nl] = a[j] * inv;
        }
    }

    // ---- stage Wl, barrier, GEMM half 0 (mean x Wl)
    const int fg = tid & 15;
    const int ng = tid >> 4;
    float acc[4][4] = {};

    {
        const float4* W4 = (const float4*)Wl;
#pragma unroll
        for (int i = 0; i < 4; ++i) {
            int idx = i * 256 + tid;
            int f = idx & 63, cc = idx >> 6;
            float4 w = W4[f * 16 + cc];
            int k0 = cc * 4;
            Wlds[(k0 + 0) * 64 + f] = w.x;
            Wlds[(k0 + 1) * 64 + f] = w.y;
            Wlds[(k0 + 2) * 64 + f] = w.z;
            Wlds[(k0 + 3) * 64 + f] = w.w;
        }
    }
    __syncthreads();
#pragma unroll 8
    for (int k = 0; k < 64; ++k) {
        const float4 a = *(const float4*)(Alds + k * 64 + (ng << 2));
        const float4 w = *(const float4*)(Wlds + k * 64 + (fg << 2));
        const float av[4] = {a.x, a.y, a.z, a.w};
        const float wv4[4] = {w.x, w.y, w.z, w.w};
#pragma unroll
        for (int i = 0; i < 4; ++i)
#pragma unroll
            for (int j = 0; j < 4; ++j)
                acc[i][j] = fmaf(av[i], wv4[j], acc[i][j]);
    }
    __syncthreads();

    // ---- stage A2 (+fused BN) and Wr, barrier, GEMM half 1
    {
        const float4* W4 = (const float4*)Wr;
#pragma unroll
        for (int i = 0; i < 4; ++i) {
            int idx = i * 256 + tid;
            int f = idx & 63, cc = idx >> 6;
            float4 w = W4[f * 16 + cc];
            int k0 = cc * 4;
            Wlds[(k0 + 0) * 64 + f] = w.x;
            Wlds[(k0 + 1) * 64 + f] = w.y;
            Wlds[(k0 + 2) * 64 + f] = w.z;
            Wlds[(k0 + 3) * 64 + f] = w.w;
        }
        const float4* A4 = (const float4*)A2;
#pragma unroll
        for (int i = 0; i < 4; ++i) {
            int idx = i * 256 + tid;
            int node = idx & 63, cc = idx >> 6;
            int gn = base + node; if (gn > NN - 1) gn = NN - 1;
            float4 a = A4[gn * 16 + cc];
            if (sc) {
                float4 s4 = ((const float4*)sc)[cc];
                float4 h4 = ((const float4*)sh)[cc];
                a.x = fmaxf(fmaf(a.x, s4.x, h4.x), 0.f);
                a.y = fmaxf(fmaf(a.y, s4.y, h4.y), 0.f);
                a.z = fmaxf(fmaf(a.z, s4.z, h4.z), 0.f);
                a.w = fmaxf(fmaf(a.w, s4.w, h4.w), 0.f);
            }
            int k0 = cc * 4;
            Alds[(k0 + 0) * 64 + node] = a.x;
            Alds[(k0 + 1) * 64 + node] = a.y;
            Alds[(k0 + 2) * 64 + node] = a.z;
            Alds[(k0 + 3) * 64 + node] = a.w;
        }
    }
    __syncthreads();
#pragma unroll 8
    for (int k = 0; k < 64; ++k) {
        const float4 a = *(const float4*)(Alds + k * 64 + (ng << 2));
        const float4 w = *(const float4*)(Wlds + k * 64 + (fg << 2));
        const float av[4] = {a.x, a.y, a.z, a.w};
        const float wv4[4] = {w.x, w.y, w.z, w.w};
#pragma unroll
        for (int i = 0; i < 4; ++i)
#pragma unroll
            for (int j = 0; j < 4; ++j)
                acc[i][j] = fmaf(av[i], wv4[j], acc[i][j]);
    }

    // ---- epilogue: bias, row L2-norm, write (+bf16), BN stat partials
    const float4 b4 = ((const float4*)bias)[fg];
    float ss[4];
#pragma unroll
    for (int i = 0; i < 4; ++i) {
        acc[i][0] += b4.x; acc[i][1] += b4.y; acc[i][2] += b4.z; acc[i][3] += b4.w;
        ss[i] = acc[i][0] * acc[i][0] + acc[i][1] * acc[i][1] +
                acc[i][2] * acc[i][2] + acc[i][3] * acc[i][3];
    }
#pragma unroll
    for (int m = 1; m <= 8; m <<= 1) {
#pragma unroll
        for (int i = 0; i < 4; ++i) ss[i] += __shfl_xor(ss[i], m, 64);
    }
    float sj[4] = {0.f, 0.f, 0.f, 0.f}, qj[4] = {0.f, 0.f, 0.f, 0.f};
#pragma unroll
    for (int i = 0; i < 4; ++i) {
        float inv = 1.0f / fmaxf(sqrtf(ss[i]), 1e-12f);
        int gn = base + (ng << 2) + i;
        bool valid = (gn < NN);
        float o0 = acc[i][0] * inv, o1 = acc[i][1] * inv;
        float o2 = acc[i][2] * inv, o3 = acc[i][3] * inv;
        if (valid) {
            ((float4*)out)[gn * 16 + fg] = make_float4(o0, o1, o2, o3);
            if (outbf)
                outbf[gn * 16 + fg] = make_ushort4(bf16_of(o0), bf16_of(o1),
                                                   bf16_of(o2), bf16_of(o3));
            sj[0] += o0; sj[1] += o1; sj[2] += o2; sj[3] += o3;
            qj[0] += o0 * o0; qj[1] += o1 * o1; qj[2] += o2 * o2; qj[3] += o3 * o3;
        }
    }
#pragma unroll
    for (int m = 16; m <= 32; m <<= 1) {
#pragma unroll
        for (int j = 0; j < 4; ++j) {
            sj[j] += __shfl_xor(sj[j], m, 64);
            qj[j] += __shfl_xor(qj[j], m, 64);
        }
    }
    __syncthreads();
    float* sblk = Alds;
    float* qblk = Alds + 64;
    if (tid < 128) Alds[tid] = 0.0f;
    __syncthreads();
    if ((tid & 63) < 16) {
#pragma unroll
        for (int j = 0; j < 4; ++j) {
            atomicAdd(&sblk[fg * 4 + j], sj[j]);
            atomicAdd(&qblk[fg * 4 + j], qj[j]);
        }
    }
    __syncthreads();
    if (tid < 64) {
        atomicAdd(&sumf[tid], sblk[tid]);
        atomicAdd(&ssqf[tid], qblk[tid]);
    }
}

// ---------------- BN finalize ----------------

__global__ void k_bnfin(const float* __restrict__ sumf, const float* __restrict__ ssqf,
                        const float* __restrict__ g, const float* __restrict__ be,
                        float* __restrict__ scale, float* __restrict__ shift) {
    int f = threadIdx.x;  // 64
    float mu = sumf[f] / (float)NN;
    float var = ssqf[f] / (float)NN - mu * mu;
    var = fmaxf(var, 0.0f);
    float sc = g[f] / sqrtf(var + 1e-5f);
    scale[f] = sc;
    shift[f] = be[f] - mu * sc;
}

// ---------------- layer-3 projection ----------------
__global__ __launch_bounds__(256)
void k_project(const float* __restrict__ h,
               const float* __restrict__ sc, const float* __restrict__ sh,
               const float* __restrict__ Wl, const float* __restrict__ Wr,
               const float* __restrict__ bias,
               float* __restrict__ zl, float* __restrict__ zr) {
    __shared__ float Alds[64 * 128];
    __shared__ float Wlds[64 * 32];
    const int tid = threadIdx.x;
    const int base = blockIdx.x * 128;

#pragma unroll
    for (int i = 0; i < 8; ++i) {
        int idx = i * 256 + tid;
        int f = idx & 31, k = idx >> 5;
        float v = 0.0f;
        if (f < 16) { if (f < 10) v = Wl[f * 64 + k]; }
        else        { if (f - 16 < 10) v = Wr[(f - 16) * 64 + k]; }
        Wlds[k * 32 + f] = v;
    }
    {
        const float4* h4 = (const float4*)h;
        const float4* sc4p = (const float4*)sc;
        const float4* sh4p = (const float4*)sh;
#pragma unroll
        for (int i = 0; i < 8; ++i) {
            int idx = i * 256 + tid;
            int node = idx & 127, c = idx >> 7;
            int gn = base + node; if (gn > NN - 1) gn = NN - 1;
            float4 a = h4[gn * 16 + c];
            float4 s4 = sc4p[c], t4 = sh4p[c];
            a.x = fmaxf(fmaf(a.x, s4.x, t4.x), 0.f);
            a.y = fmaxf(fmaf(a.y, s4.y, t4.y), 0.f);
            a.z = fmaxf(fmaf(a.z, s4.z, t4.z), 0.f);
            a.w = fmaxf(fmaf(a.w, s4.w, t4.w), 0.f);
            int k0 = c * 4;
            Alds[(k0 + 0) * 128 + node] = a.x;
            Alds[(k0 + 1) * 128 + node] = a.y;
            Alds[(k0 + 2) * 128 + node] = a.z;
            Alds[(k0 + 3) * 128 + node] = a.w;
        }
    }
    __syncthreads();

    const int fg = tid & 7;
    const int ng = tid >> 3;

    float acc[4][4] = {};
#pragma unroll 4
    for (int k = 0; k < 64; ++k) {
        const float4 a = *(const float4*)(Alds + k * 128 + (ng << 2));
        const float4 w = *(const float4*)(Wlds + k * 32 + (fg << 2));
        const float av[4] = {a.x, a.y, a.z, a.w};
        const float wv[4] = {w.x, w.y, w.z, w.w};
#pragma unroll
        for (int i = 0; i < 4; ++i)
#pragma unroll
            for (int j = 0; j < 4; ++j)
                acc[i][j] = fmaf(av[i], wv[j], acc[i][j]);
    }

    if (fg == 3 || fg == 7) return;
    float4* dst = (fg < 4) ? (float4*)zl : (float4*)zr;
    int fq = (fg < 4) ? fg : fg - 4;
    float bx = 0.f, by = 0.f, bz = 0.f, bw = 0.f;
    if (fg >= 4) {
        int f0 = fq * 4;
        bx = (f0 + 0 < 10) ? bias[f0 + 0] : 0.f;
        by = (f0 + 1 < 10) ? bias[f0 + 1] : 0.f;
        bz = (f0 + 2 < 10) ? bias[f0 + 2] : 0.f;
        bw = (f0 + 3 < 10) ? bias[f0 + 3] : 0.f;
    }
#pragma unroll
    for (int i = 0; i < 4; ++i) {
        int gn = base + (ng << 2) + i;
        if (gn < NN)
            dst[gn * 3 + fq] = make_float4(acc[i][0] + bx, acc[i][1] + by,
                                           acc[i][2] + bz, acc[i][3] + bw);
    }
}

// ---------------- layer-3 aggregation ----------------
__global__ __launch_bounds__(256)
void k_agg10(const int* __restrict__ rs, const int* __restrict__ esrc,
             const float* __restrict__ zl, const float* __restrict__ zr,
             float* __restrict__ out) {
    int gid = blockIdx.x * 256 + threadIdx.x;
    unsigned node = (unsigned)gid / 3u;
    int j = gid - (int)node * 3;
    if (node >= NN) return;
    int s0 = rs[node], s1 = rs[node + 1];
    const float4* zl4 = (const float4*)zl;
    float4 acc = make_float4(0.f, 0.f, 0.f, 0.f);
    for (int p = s0; p < s1; ++p) {
        float4 v = zl4[esrc[p] * 3 + j];
        acc.x += v.x; acc.y += v.y; acc.z += v.z; acc.w += v.w;
    }
    int cnt = s1 - s0; if (cnt < 1) cnt = 1;
    float inv = 1.0f / (float)cnt;
    float4 r = ((const float4*)zr)[node * 3 + j];
    r.x = fmaf(acc.x, inv, r.x); r.y = fmaf(acc.y, inv, r.y);
    r.z = fmaf(acc.z, inv, r.z); r.w = fmaf(acc.w, inv, r.w);
    float2* o2 = (float2*)(out + (size_t)node * 10);
    if (j < 2) {
        o2[j * 2 + 0] = make_float2(r.x, r.y);
        o2[j * 2 + 1] = make_float2(r.z, r.w);
    } else {
        o2[4] = make_float2(r.x, r.y);
    }
}

// ---------------- launch ----------------

extern "C" void kernel_launch(void* const* d_in, const int* in_sizes, int n_in,
                              void* d_out, int out_size, void* d_ws, size_t ws_size,
                              hipStream_t stream) {
    const float* x   = (const float*)d_in[0];
    const int*   ei  = (const int*)d_in[1];
    const float* Wl1 = (const float*)d_in[2];
    const float* Wr1 = (const float*)d_in[3];
    const float* b1  = (const float*)d_in[4];
    const float* g1  = (const float*)d_in[5];
    const float* be1 = (const float*)d_in[6];
    const float* Wl2 = (const float*)d_in[7];
    const float* Wr2 = (const float*)d_in[8];
    const float* b2  = (const float*)d_in[9];
    const float* g2  = (const float*)d_in[10];
    const float* be2 = (const float*)d_in[11];
    const float* Wl3 = (const float*)d_in[12];
    const float* Wr3 = (const float*)d_in[13];
    const float* b3  = (const float*)d_in[14];
    float* out = (float*)d_out;

    char* w = (char*)d_ws;
    auto alloc = [&](size_t bytes) -> void* {
        void* p = (void*)w;
        w += (bytes + 255) & ~(size_t)255;
        return p;
    };
    int*   ccount = (int*)alloc(256 * 4);
    int*   cbase  = (int*)alloc(256 * 4);
    int*   gcur   = (int*)alloc(256 * 4);
    int*   rs     = (int*)alloc((size_t)(NN + 1) * 4);
    int*   esrc   = (int*)alloc((size_t)EE * 4);
    float* scratch= (float*)alloc((size_t)NN * 64 * 4);   // pairs / zl / zr
    float* h1     = (float*)alloc((size_t)NN * 64 * 4);
    unsigned short* xbf  = (unsigned short*)alloc((size_t)NN * 64 * 2);
    unsigned short* h1bf = (unsigned short*)alloc((size_t)NN * 64 * 2);
    float* stats  = (float*)alloc(256 * 4);  // sum1, ssq1, sum2, ssq2
    float* scsh   = (float*)alloc(256 * 4);  // scale1, shift1, scale2, shift2
    int2*  pairs  = (int2*)scratch;
    float* zl     = scratch;
    float* zr     = scratch + (size_t)NN * 12;

    hipMemsetAsync(ccount, 0, 256 * 4, stream);
    hipMemsetAsync(stats, 0, 256 * 4, stream);

    k_ccount<<<NCH, 256, 0, stream>>>(ei, ccount);
    k_cscan<<<1, 256, 0, stream>>>(ccount, cbase, gcur);
    k_coarse<<<NCH, 256, 0, stream>>>(ei, gcur, pairs);
    k_fine<<<NBKT, 512, 0, stream>>>(cbase, pairs, rs, esrc);
    k_tobf<<<(NN * 16 + 255) / 256, 256, 0, stream>>>((const float4*)x, (ushort4*)xbf);

    const int sageBlocks = (NN + 63) / 64;       // 1563
    const int projBlocks = (NN + 127) / 128;     // 782
    const int a10Blocks  = (NN * 3 + 255) / 256; // 1172

    // layer 1: fused gather(xbf) + GEMM(x) -> h1 fp32 + h1bf
    k_sagefused<<<sageBlocks, 256, 0, stream>>>(xbf, x, Wl1, Wr1, b1, h1, (ushort4*)h1bf,
                                                stats + 0, stats + 64, nullptr, nullptr,
                                                rs, esrc);
    k_bnfin<<<1, 64, 0, stream>>>(stats + 0, stats + 64, g1, be1, scsh + 0, scsh + 64);

    // layer 2: fused gather(h1bf, BN1+ReLU) + GEMM(h1, BN1+ReLU) -> h1 in place
    k_sagefused<<<sageBlocks, 256, 0, stream>>>(h1bf, h1, Wl2, Wr2, b2, h1, nullptr,
                                                stats + 128, stats + 192, scsh + 0, scsh + 64,
                                                rs, esrc);
    k_bnfin<<<1, 64, 0, stream>>>(stats + 128, stats + 192, g2, be2, scsh + 128, scsh + 192);

    // layer 3: project (BN2+ReLU fused) then 10-dim aggregate
    k_project<<<projBlocks, 256, 0, stream>>>(h1, scsh + 128, scsh + 192,
                                              Wl3, Wr3, b3, zl, zr);
    k_agg10<<<a10Blocks, 256, 0, stream>>>(rs, esrc, zl, zr, out);
}

// Round 7
// 384.716 us; speedup vs baseline: 1.1109x; 1.1109x over previous
//
#include <hip/hip_runtime.h>
#include <hip/hip_bf16.h>

#define NN 100000
#define EE 1600000
#define BSZ 512    // dst-nodes per coarse bucket
#define NBKT 196   // ceil(NN/BSZ)
#define CHUNK 8192 // edges per coarse chunk
#define NCH 196    // ceil(EE/CHUNK)

typedef short bf16x8 __attribute__((ext_vector_type(8)));
typedef float f32x4 __attribute__((ext_vector_type(4)));

// ---------------- bf16 helpers ----------------
__device__ inline unsigned short bf16_of(float f) {
    __hip_bfloat16 h = __float2bfloat16(f);   // RNE
    return *reinterpret_cast<unsigned short*>(&h);
}
__device__ inline unsigned pack2(float a, float b) {
    return (unsigned)bf16_of(a) | ((unsigned)bf16_of(b) << 16);
}
__device__ inline float bflo(unsigned u) { return __uint_as_float(u << 16); }
__device__ inline float bfhi(unsigned u) { return __uint_as_float(u & 0xffff0000u); }

// ---------------- CSR build ----------------

__global__ __launch_bounds__(256)
void k_ccount(const int* __restrict__ ei, int* __restrict__ ccount) {
    __shared__ int hist[NBKT];
    int tid = threadIdx.x;
    int e0 = blockIdx.x * CHUNK;
    int e1 = e0 + CHUNK; if (e1 > EE) e1 = EE;
    for (int i = tid; i < NBKT; i += 256) hist[i] = 0;
    __syncthreads();
    for (int e = e0 + tid; e < e1; e += 256)
        atomicAdd(&hist[ei[EE + e] >> 9], 1);
    __syncthreads();
    for (int i = tid; i < NBKT; i += 256)
        if (hist[i]) atomicAdd(&ccount[i], hist[i]);
}

__global__ void k_cscan(const int* __restrict__ ccount, int* __restrict__ cbase,
                        int* __restrict__ gcur) {
    __shared__ int s[256];
    int tid = threadIdx.x;
    int v = (tid < NBKT) ? ccount[tid] : 0;
    s[tid] = v;
    __syncthreads();
    for (int off = 1; off < 256; off <<= 1) {
        int t = (tid >= off) ? s[tid - off] : 0;
        __syncthreads();
        if (tid >= off) s[tid] += t;
        __syncthreads();
    }
    if (tid < NBKT) {
        int excl = s[tid] - v;
        cbase[tid] = excl;
        gcur[tid] = excl;
    }
    if (tid == NBKT - 1) cbase[NBKT] = s[tid];
}

__global__ __launch_bounds__(256)
void k_coarse(const int* __restrict__ ei, int* __restrict__ gcur, int2* __restrict__ pairs) {
    __shared__ int hist[NBKT];
    __shared__ int base[NBKT];
    __shared__ int curs[NBKT];
    int tid = threadIdx.x;
    int e0 = blockIdx.x * CHUNK;
    int e1 = e0 + CHUNK; if (e1 > EE) e1 = EE;
    for (int i = tid; i < NBKT; i += 256) hist[i] = 0;
    __syncthreads();
    for (int e = e0 + tid; e < e1; e += 256)
        atomicAdd(&hist[ei[EE + e] >> 9], 1);
    __syncthreads();
    for (int i = tid; i < NBKT; i += 256) {
        base[i] = atomicAdd(&gcur[i], hist[i]);
        curs[i] = 0;
    }
    __syncthreads();
    for (int e = e0 + tid; e < e1; e += 256) {
        int src = ei[e];
        int dst = ei[EE + e];
        int b = dst >> 9;
        int off = atomicAdd(&curs[b], 1);
        pairs[base[b] + off] = make_int2(src, dst);
    }
}

__global__ __launch_bounds__(512)
void k_fine(const int* __restrict__ cbase, const int2* __restrict__ pairs,
            int* __restrict__ rs, int* __restrict__ esrc) {
    __shared__ int deg[BSZ];
    __shared__ int s[BSZ];
    int b = blockIdx.x;
    int n0 = b * BSZ;
    int nlocal = NN - n0; if (nlocal > BSZ) nlocal = BSZ;
    int tid = threadIdx.x;
    deg[tid] = 0;
    __syncthreads();
    int e0 = cbase[b], e1 = cbase[b + 1];
    for (int e = e0 + tid; e < e1; e += 512)
        atomicAdd(&deg[pairs[e].y - n0], 1);
    __syncthreads();
    int v = deg[tid];
    s[tid] = v;
    __syncthreads();
    for (int off = 1; off < 512; off <<= 1) {
        int t = (tid >= off) ? s[tid - off] : 0;
        __syncthreads();
        if (tid >= off) s[tid] += t;
        __syncthreads();
    }
    int excl = s[tid] - v;
    if (tid < nlocal) rs[n0 + tid] = e0 + excl;
    if (b == NBKT - 1 && tid == 0) rs[NN] = EE;
    deg[tid] = e0 + excl;
    __syncthreads();
    for (int e = e0 + tid; e < e1; e += 512) {
        int2 p = pairs[e];
        int pos = atomicAdd(&deg[p.y - n0], 1);
        esrc[pos] = p.x;
    }
}

// ---------------- fp32 -> bf16 table conversion ----------------
__global__ void k_tobf(const float4* __restrict__ src, ushort4* __restrict__ dst) {
    int i = blockIdx.x * 256 + threadIdx.x;
    if (i >= NN * 16) return;
    float4 v = src[i];
    dst[i] = make_ushort4(bf16_of(v.x), bf16_of(v.y), bf16_of(v.z), bf16_of(v.w));
}

// ---------------- aggregation (64-dim) over bf16 table -> bf16 mean ----------------
// One wave per node: 8 feature-lanes (8 feats, 16B) x 8 neighbor slots.
__global__ __launch_bounds__(256)
void k_aggbf(const unsigned short* __restrict__ xbf, const int* __restrict__ rs,
             const int* __restrict__ esrc, unsigned short* __restrict__ meanbf,
             const float* __restrict__ sc, const float* __restrict__ sh) {
    int gid = blockIdx.x * 256 + threadIdx.x;
    int node = gid >> 6;
    if (node >= NN) return;
    int lane = threadIdx.x & 63;
    int c = lane & 7;         // feature octet
    int slot = lane >> 3;     // neighbor slot 0..7
    int s0 = rs[node], s1 = rs[node + 1];
    const uint4* xb = (const uint4*)xbf;
    float a0 = 0.f, a1 = 0.f, a2 = 0.f, a3 = 0.f, a4 = 0.f, a5 = 0.f, a6 = 0.f, a7 = 0.f;
    if (sc) {
        float4 scl = ((const float4*)sc)[2 * c], sch = ((const float4*)sc)[2 * c + 1];
        float4 shl = ((const float4*)sh)[2 * c], shh = ((const float4*)sh)[2 * c + 1];
        for (int p = s0 + slot; p < s1; p += 8) {
            uint4 v = xb[esrc[p] * 8 + c];
            a0 += fmaxf(fmaf(bflo(v.x), scl.x, shl.x), 0.f);
            a1 += fmaxf(fmaf(bfhi(v.x), scl.y, shl.y), 0.f);
            a2 += fmaxf(fmaf(bflo(v.y), scl.z, shl.z), 0.f);
            a3 += fmaxf(fmaf(bfhi(v.y), scl.w, shl.w), 0.f);
            a4 += fmaxf(fmaf(bflo(v.z), sch.x, shh.x), 0.f);
            a5 += fmaxf(fmaf(bfhi(v.z), sch.y, shh.y), 0.f);
            a6 += fmaxf(fmaf(bflo(v.w), sch.z, shh.z), 0.f);
            a7 += fmaxf(fmaf(bfhi(v.w), sch.w, shh.w), 0.f);
        }
    } else {
        for (int p = s0 + slot; p < s1; p += 8) {
            uint4 v = xb[esrc[p] * 8 + c];
            a0 += bflo(v.x); a1 += bfhi(v.x);
            a2 += bflo(v.y); a3 += bfhi(v.y);
            a4 += bflo(v.z); a5 += bfhi(v.z);
            a6 += bflo(v.w); a7 += bfhi(v.w);
        }
    }
#pragma unroll
    for (int m = 8; m <= 32; m <<= 1) {
        a0 += __shfl_xor(a0, m, 64); a1 += __shfl_xor(a1, m, 64);
        a2 += __shfl_xor(a2, m, 64); a3 += __shfl_xor(a3, m, 64);
        a4 += __shfl_xor(a4, m, 64); a5 += __shfl_xor(a5, m, 64);
        a6 += __shfl_xor(a6, m, 64); a7 += __shfl_xor(a7, m, 64);
    }
    if (slot == 0) {
        int cnt = s1 - s0; if (cnt < 1) cnt = 1;
        float inv = 1.0f / (float)cnt;
        uint4 o;
        o.x = pack2(a0 * inv, a1 * inv);
        o.y = pack2(a2 * inv, a3 * inv);
        o.z = pack2(a4 * inv, a5 * inv);
        o.w = pack2(a6 * inv, a7 * inv);
        ((uint4*)meanbf)[node * 8 + c] = o;
    }
}

// ---------------- SAGE layer: bf16 MFMA GEMM + bias + L2-norm + BN stats ----------------
// tile = 64 nodes x 64 feats, K=128 (mean||A2). A rows / W rows in LDS, stride
// 136 shorts (16B-aligned, b128 frag reads stay at the 8-cycle floor).
// Wave w: nodes w*16..+15; 4 n-tiles x 4 k-chunks = 16 MFMAs.
__global__ __launch_bounds__(256, 4)
void k_sagemfma(const unsigned short* __restrict__ meanbf,  // (N,64) bf16
                const unsigned short* __restrict__ a2bf,    // (N,64) bf16 (x / h1raw)
                const float* __restrict__ Wl, const float* __restrict__ Wr,
                const float* __restrict__ bias,
                float* __restrict__ out, unsigned short* __restrict__ outbf,
                float* __restrict__ sumf, float* __restrict__ ssqf,
                const float* __restrict__ sc, const float* __restrict__ sh) {
    __shared__ short Alds[64 * 136];
    __shared__ short Wlds[64 * 136];
    __shared__ float sblk[64];
    __shared__ float qblk[64];
    const int tid = threadIdx.x;
    const int base = blockIdx.x * 64;

    if (tid < 64) { sblk[tid] = 0.f; qblk[tid] = 0.f; }

    // ---- stage mean (k 0..63) and A2 (k 64..127), bf16, node-major rows
    {
        const uint4* mb = (const uint4*)meanbf;
        const uint4* ab = (const uint4*)a2bf;
#pragma unroll
        for (int i = 0; i < 2; ++i) {
            int idx = i * 256 + tid;          // 0..511
            int row = idx & 63, cb = idx >> 6; // cb 0..7
            int gn = base + row; if (gn > NN - 1) gn = NN - 1;
            uint4 v = mb[gn * 8 + cb];
            *(uint4*)(Alds + row * 136 + cb * 8) = v;
            uint4 u = ab[gn * 8 + cb];
            if (sc) {
                float4 sA = ((const float4*)sc)[cb * 2], sB = ((const float4*)sc)[cb * 2 + 1];
                float4 hA = ((const float4*)sh)[cb * 2], hB = ((const float4*)sh)[cb * 2 + 1];
                float f0 = fmaxf(fmaf(bflo(u.x), sA.x, hA.x), 0.f);
                float f1 = fmaxf(fmaf(bfhi(u.x), sA.y, hA.y), 0.f);
                float f2 = fmaxf(fmaf(bflo(u.y), sA.z, hA.z), 0.f);
                float f3 = fmaxf(fmaf(bfhi(u.y), sA.w, hA.w), 0.f);
                float f4 = fmaxf(fmaf(bflo(u.z), sB.x, hB.x), 0.f);
                float f5 = fmaxf(fmaf(bfhi(u.z), sB.y, hB.y), 0.f);
                float f6 = fmaxf(fmaf(bflo(u.w), sB.z, hB.z), 0.f);
                float f7 = fmaxf(fmaf(bfhi(u.w), sB.w, hB.w), 0.f);
                u.x = pack2(f0, f1); u.y = pack2(f2, f3);
                u.z = pack2(f4, f5); u.w = pack2(f6, f7);
            }
            *(uint4*)(Alds + row * 136 + 64 + cb * 8) = u;
        }
    }
    // ---- stage Wl (k 0..63) and Wr (k 64..127), fp32 -> bf16
    {
        const float4* Wl4 = (const float4*)Wl;
        const float4* Wr4 = (const float4*)Wr;
#pragma unroll
        for (int i = 0; i < 4; ++i) {
            int idx = i * 256 + tid;          // 0..1023
            int row = idx >> 4, j = idx & 15; // j: float4 index (k = j*4)
            float4 wv = Wl4[row * 16 + j];
            *(ushort4*)(Wlds + row * 136 + j * 4) =
                make_ushort4(bf16_of(wv.x), bf16_of(wv.y), bf16_of(wv.z), bf16_of(wv.w));
            float4 wr = Wr4[row * 16 + j];
            *(ushort4*)(Wlds + row * 136 + 64 + j * 4) =
                make_ushort4(bf16_of(wr.x), bf16_of(wr.y), bf16_of(wr.z), bf16_of(wr.w));
        }
    }
    __syncthreads();

    const int col = tid & 15;        // N-dim lane (feat within tile) / M-dim for A
    const int q   = (tid >> 4) & 3;  // k-quad
    const int w   = tid >> 6;        // wave -> node strip w*16..+15

    const short* arow = Alds + (w * 16 + col) * 136 + q * 8;
    const short* b0p = Wlds + (0 * 16 + col) * 136 + q * 8;
    const short* b1p = Wlds + (1 * 16 + col) * 136 + q * 8;
    const short* b2p = Wlds + (2 * 16 + col) * 136 + q * 8;
    const short* b3p = Wlds + (3 * 16 + col) * 136 + q * 8;

    f32x4 acc0 = {0.f, 0.f, 0.f, 0.f}, acc1 = acc0, acc2 = acc0, acc3 = acc0;
#pragma unroll
    for (int c = 0; c < 4; ++c) {
        bf16x8 a  = *(const bf16x8*)(arow + c * 32);
        bf16x8 b0 = *(const bf16x8*)(b0p + c * 32);
        bf16x8 b1 = *(const bf16x8*)(b1p + c * 32);
        bf16x8 b2 = *(const bf16x8*)(b2p + c * 32);
        bf16x8 b3 = *(const bf16x8*)(b3p + c * 32);
        acc0 = __builtin_amdgcn_mfma_f32_16x16x32_bf16(a, b0, acc0, 0, 0, 0);
        acc1 = __builtin_amdgcn_mfma_f32_16x16x32_bf16(a, b1, acc1, 0, 0, 0);
        acc2 = __builtin_amdgcn_mfma_f32_16x16x32_bf16(a, b2, acc2, 0, 0, 0);
        acc3 = __builtin_amdgcn_mfma_f32_16x16x32_bf16(a, b3, acc3, 0, 0, 0);
    }

    // ---- epilogue (C-layout: row=q*4+reg is node, col=lane&15 is feat)
    float bb0 = bias[col], bb1 = bias[16 + col], bb2 = bias[32 + col], bb3 = bias[48 + col];
    float sj0 = 0.f, sj1 = 0.f, sj2 = 0.f, sj3 = 0.f;
    float qj0 = 0.f, qj1 = 0.f, qj2 = 0.f, qj3 = 0.f;
#pragma unroll
    for (int r = 0; r < 4; ++r) {
        int gn = base + w * 16 + q * 4 + r;
        float o0 = acc0[r] + bb0, o1 = acc1[r] + bb1;
        float o2 = acc2[r] + bb2, o3 = acc3[r] + bb3;
        float ssv = o0 * o0 + o1 * o1 + o2 * o2 + o3 * o3;
        ssv += __shfl_xor(ssv, 1, 64);
        ssv += __shfl_xor(ssv, 2, 64);
        ssv += __shfl_xor(ssv, 4, 64);
        ssv += __shfl_xor(ssv, 8, 64);
        float inv = 1.0f / fmaxf(sqrtf(ssv), 1e-12f);
        o0 *= inv; o1 *= inv; o2 *= inv; o3 *= inv;
        if (gn < NN) {
            out[gn * 64 + col]      = o0;
            out[gn * 64 + 16 + col] = o1;
            out[gn * 64 + 32 + col] = o2;
            out[gn * 64 + 48 + col] = o3;
            if (outbf) {
                outbf[gn * 64 + col]      = bf16_of(o0);
                outbf[gn * 64 + 16 + col] = bf16_of(o1);
                outbf[gn * 64 + 32 + col] = bf16_of(o2);
                outbf[gn * 64 + 48 + col] = bf16_of(o3);
            }
            sj0 += o0; sj1 += o1; sj2 += o2; sj3 += o3;
            qj0 += o0 * o0; qj1 += o1 * o1; qj2 += o2 * o2; qj3 += o3 * o3;
        }
    }
#pragma unroll
    for (int m = 16; m <= 32; m <<= 1) {
        sj0 += __shfl_xor(sj0, m, 64); sj1 += __shfl_xor(sj1, m, 64);
        sj2 += __shfl_xor(sj2, m, 64); sj3 += __shfl_xor(sj3, m, 64);
        qj0 += __shfl_xor(qj0, m, 64); qj1 += __shfl_xor(qj1, m, 64);
        qj2 += __shfl_xor(qj2, m, 64); qj3 += __shfl_xor(qj3, m, 64);
    }
    if (q == 0) {
        atomicAdd(&sblk[col], sj0);      atomicAdd(&qblk[col], qj0);
        atomicAdd(&sblk[16 + col], sj1); atomicAdd(&qblk[16 + col], qj1);
        atomicAdd(&sblk[32 + col], sj2); atomicAdd(&qblk[32 + col], qj2);
        atomicAdd(&sblk[48 + col], sj3); atomicAdd(&qblk[48 + col], qj3);
    }
    __syncthreads();
    if (tid < 64) {
        atomicAdd(&sumf[tid], sblk[tid]);
        atomicAdd(&ssqf[tid], qblk[tid]);
    }
}

// ---------------- BN finalize ----------------

__global__ void k_bnfin(const float* __restrict__ sumf, const float* __restrict__ ssqf,
                        const float* __restrict__ g, const float* __restrict__ be,
                        float* __restrict__ scale, float* __restrict__ shift) {
    int f = threadIdx.x;  // 64
    float mu = sumf[f] / (float)NN;
    float var = ssqf[f] / (float)NN - mu * mu;
    var = fmaxf(var, 0.0f);
    float sc = g[f] / sqrtf(var + 1e-5f);
    scale[f] = sc;
    shift[f] = be[f] - mu * sc;
}

// ---------------- layer-3 projection ----------------
__global__ __launch_bounds__(256)
void k_project(const float* __restrict__ h,
               const float* __restrict__ sc, const float* __restrict__ sh,
               const float* __restrict__ Wl, const float* __restrict__ Wr,
               const float* __restrict__ bias,
               float* __restrict__ zl, float* __restrict__ zr) {
    __shared__ float Alds[64 * 128];
    __shared__ float Wlds[64 * 32];
    const int tid = threadIdx.x;
    const int base = blockIdx.x * 128;

#pragma unroll
    for (int i = 0; i < 8; ++i) {
        int idx = i * 256 + tid;
        int f = idx & 31, k = idx >> 5;
        float v = 0.0f;
        if (f < 16) { if (f < 10) v = Wl[f * 64 + k]; }
        else        { if (f - 16 < 10) v = Wr[(f - 16) * 64 + k]; }
        Wlds[k * 32 + f] = v;
    }
    {
        const float4* h4 = (const float4*)h;
        const float4* sc4p = (const float4*)sc;
        const float4* sh4p = (const float4*)sh;
#pragma unroll
        for (int i = 0; i < 8; ++i) {
            int idx = i * 256 + tid;
            int node = idx & 127, c = idx >> 7;
            int gn = base + node; if (gn > NN - 1) gn = NN - 1;
            float4 a = h4[gn * 16 + c];
            float4 s4 = sc4p[c], t4 = sh4p[c];
            a.x = fmaxf(fmaf(a.x, s4.x, t4.x), 0.f);
            a.y = fmaxf(fmaf(a.y, s4.y, t4.y), 0.f);
            a.z = fmaxf(fmaf(a.z, s4.z, t4.z), 0.f);
            a.w = fmaxf(fmaf(a.w, s4.w, t4.w), 0.f);
            int k0 = c * 4;
            Alds[(k0 + 0) * 128 + node] = a.x;
            Alds[(k0 + 1) * 128 + node] = a.y;
            Alds[(k0 + 2) * 128 + node] = a.z;
            Alds[(k0 + 3) * 128 + node] = a.w;
        }
    }
    __syncthreads();

    const int fg = tid & 7;
    const int ng = tid >> 3;

    float acc[4][4] = {};
#pragma unroll 4
    for (int k = 0; k < 64; ++k) {
        const float4 a = *(const float4*)(Alds + k * 128 + (ng << 2));
        const float4 w = *(const float4*)(Wlds + k * 32 + (fg << 2));
        const float av[4] = {a.x, a.y, a.z, a.w};
        const float wv[4] = {w.x, w.y, w.z, w.w};
#pragma unroll
        for (int i = 0; i < 4; ++i)
#pragma unroll
            for (int j = 0; j < 4; ++j)
                acc[i][j] = fmaf(av[i], wv[j], acc[i][j]);
    }

    if (fg == 3 || fg == 7) return;
    float4* dst = (fg < 4) ? (float4*)zl : (float4*)zr;
    int fq = (fg < 4) ? fg : fg - 4;
    float bx = 0.f, by = 0.f, bz = 0.f, bw = 0.f;
    if (fg >= 4) {
        int f0 = fq * 4;
        bx = (f0 + 0 < 10) ? bias[f0 + 0] : 0.f;
        by = (f0 + 1 < 10) ? bias[f0 + 1] : 0.f;
        bz = (f0 + 2 < 10) ? bias[f0 + 2] : 0.f;
        bw = (f0 + 3 < 10) ? bias[f0 + 3] : 0.f;
    }
#pragma unroll
    for (int i = 0; i < 4; ++i) {
        int gn = base + (ng << 2) + i;
        if (gn < NN)
            dst[gn * 3 + fq] = make_float4(acc[i][0] + bx, acc[i][1] + by,
                                           acc[i][2] + bz, acc[i][3] + bw);
    }
}

// ---------------- layer-3 aggregation ----------------
__global__ __launch_bounds__(256)
void k_agg10(const int* __restrict__ rs, const int* __restrict__ esrc,
             const float* __restrict__ zl, const float* __restrict__ zr,
             float* __restrict__ out) {
    int gid = blockIdx.x * 256 + threadIdx.x;
    unsigned node = (unsigned)gid / 3u;
    int j = gid - (int)node * 3;
    if (node >= NN) return;
    int s0 = rs[node], s1 = rs[node + 1];
    const float4* zl4 = (const float4*)zl;
    float4 acc = make_float4(0.f, 0.f, 0.f, 0.f);
    for (int p = s0; p < s1; ++p) {
        float4 v = zl4[esrc[p] * 3 + j];
        acc.x += v.x; acc.y += v.y; acc.z += v.z; acc.w += v.w;
    }
    int cnt = s1 - s0; if (cnt < 1) cnt = 1;
    float inv = 1.0f / (float)cnt;
    float4 r = ((const float4*)zr)[node * 3 + j];
    r.x = fmaf(acc.x, inv, r.x); r.y = fmaf(acc.y, inv, r.y);
    r.z = fmaf(acc.z, inv, r.z); r.w = fmaf(acc.w, inv, r.w);
    float2* o2 = (float2*)(out + (size_t)node * 10);
    if (j < 2) {
        o2[j * 2 + 0] = make_float2(r.x, r.y);
        o2[j * 2 + 1] = make_float2(r.z, r.w);
    } else {
        o2[4] = make_float2(r.x, r.y);
    }
}

// ---------------- launch ----------------

extern "C" void kernel_launch(void* const* d_in, const int* in_sizes, int n_in,
                              void* d_out, int out_size, void* d_ws, size_t ws_size,
                              hipStream_t stream) {
    const float* x   = (const float*)d_in[0];
    const int*   ei  = (const int*)d_in[1];
    const float* Wl1 = (const float*)d_in[2];
    const float* Wr1 = (const float*)d_in[3];
    const float* b1  = (const float*)d_in[4];
    const float* g1  = (const float*)d_in[5];
    const float* be1 = (const float*)d_in[6];
    const float* Wl2 = (const float*)d_in[7];
    const float* Wr2 = (const float*)d_in[8];
    const float* b2  = (const float*)d_in[9];
    const float* g2  = (const float*)d_in[10];
    const float* be2 = (const float*)d_in[11];
    const float* Wl3 = (const float*)d_in[12];
    const float* Wr3 = (const float*)d_in[13];
    const float* b3  = (const float*)d_in[14];
    float* out = (float*)d_out;

    char* w = (char*)d_ws;
    auto alloc = [&](size_t bytes) -> void* {
        void* p = (void*)w;
        w += (bytes + 255) & ~(size_t)255;
        return p;
    };
    int*   ccount = (int*)alloc(256 * 4);
    int*   cbase  = (int*)alloc(256 * 4);
    int*   gcur   = (int*)alloc(256 * 4);
    int*   rs     = (int*)alloc((size_t)(NN + 1) * 4);
    int*   esrc   = (int*)alloc((size_t)EE * 4);
    float* scratch= (float*)alloc((size_t)NN * 64 * 4);   // pairs / zl / zr
    float* h1     = (float*)alloc((size_t)NN * 64 * 4);
    unsigned short* xbf    = (unsigned short*)alloc((size_t)NN * 64 * 2);
    unsigned short* h1bf   = (unsigned short*)alloc((size_t)NN * 64 * 2);
    unsigned short* meanbf = (unsigned short*)alloc((size_t)NN * 64 * 2);
    float* stats  = (float*)alloc(256 * 4);  // sum1, ssq1, sum2, ssq2
    float* scsh   = (float*)alloc(256 * 4);  // scale1, shift1, scale2, shift2
    int2*  pairs  = (int2*)scratch;
    float* zl     = scratch;
    float* zr     = scratch + (size_t)NN * 12;

    hipMemsetAsync(ccount, 0, 256 * 4, stream);
    hipMemsetAsync(stats, 0, 256 * 4, stream);

    k_ccount<<<NCH, 256, 0, stream>>>(ei, ccount);
    k_cscan<<<1, 256, 0, stream>>>(ccount, cbase, gcur);
    k_coarse<<<NCH, 256, 0, stream>>>(ei, gcur, pairs);
    k_fine<<<NBKT, 512, 0, stream>>>(cbase, pairs, rs, esrc);
    k_tobf<<<(NN * 16 + 255) / 256, 256, 0, stream>>>((const float4*)x, (ushort4*)xbf);

    const int aggBlocks  = (NN * 64) / 256;      // 25000 (1 wave / node)
    const int sageBlocks = (NN + 63) / 64;       // 1563
    const int projBlocks = (NN + 127) / 128;     // 782
    const int a10Blocks  = (NN * 3 + 255) / 256; // 1172

    // layer 1: bf16 mean of xbf; MFMA GEMM (meanbf, xbf) -> h1 fp32 + h1bf
    k_aggbf<<<aggBlocks, 256, 0, stream>>>(xbf, rs, esrc, meanbf, nullptr, nullptr);
    k_sagemfma<<<sageBlocks, 256, 0, stream>>>(meanbf, xbf, Wl1, Wr1, b1, h1, h1bf,
                                               stats + 0, stats + 64, nullptr, nullptr);
    k_bnfin<<<1, 64, 0, stream>>>(stats + 0, stats + 64, g1, be1, scsh + 0, scsh + 64);

    // layer 2: bf16 mean of relu(bn1(h1bf)); MFMA GEMM (meanbf, h1bf+BN) -> h1 in place
    k_aggbf<<<aggBlocks, 256, 0, stream>>>(h1bf, rs, esrc, meanbf, scsh + 0, scsh + 64);
    k_sagemfma<<<sageBlocks, 256, 0, stream>>>(meanbf, h1bf, Wl2, Wr2, b2, h1, nullptr,
                                               stats + 128, stats + 192, scsh + 0, scsh + 64);
    k_bnfin<<<1, 64, 0, stream>>>(stats + 128, stats + 192, g2, be2, scsh + 128, scsh + 192);

    // layer 3: project (BN2+ReLU fused) then 10-dim aggregate
    k_project<<<projBlocks, 256, 0, stream>>>(h1, scsh + 128, scsh + 192,
                                              Wl3, Wr3, b3, zl, zr);
    k_agg10<<<a10Blocks, 256, 0, stream>>>(rs, esrc, zl, zr, out);
}